// Round 6
// baseline (1373.504 us; speedup 1.0000x reference)
//
#include <hip/hip_runtime.h>

#define SL 256
#define BATCH 8
#define NT 1024
#define W0 32
#define BSTRIDE 35   // phase-A LDS band stride: 35%32=3, 34%32=2 -> <=2-way, free

// ---------------- inside phase B: widths [w0,w1], compile-time G ----------
// E[i,j] = exp(sc[i,j]) * sum_k E[i,k]*E[k,j]  (scaled linear space; scale
// telescopes). Both operands are contiguous row streams: Eg row i, EgT row j.
template <int G>
__device__ __forceinline__ void insidePh(int w0, int w1, int tid,
    const float* __restrict__ sc, float* __restrict__ Eg,
    float* __restrict__ EgT, volatile float* __restrict__ red) {
  constexpr int LG = (G == 4) ? 2 : (G == 8) ? 3 : (G == 16) ? 4 : (G == 32) ? 5 : 6;
  constexpr int NG = NT / G;
  const int c0 = tid >> LG;
  const int lig = tid & (G - 1);
  for (int w = w0; w <= w1; ++w) {
    const int cells = SL - w;
    const int fidx = 16 + (w & 1);          // ping-pong overflow flag slot
    for (int c = c0; c < cells; c += NG) {
      const int i = c, j = i + w;
      const float* ar = Eg + i * SL;        // E[i,k], contiguous in k
      const float* br = EgT + j * SL;       // E[k,j], contiguous in k
      float acc0 = 0.f, acc1 = 0.f;
      const int kA = (i + 4) & ~3;          // aligned bulk start
      {
        const int k = i + 1 + lig;          // front peel (<=3 elems)
        if (k < kA) acc0 = fmaf(ar[k], br[k], acc0);
      }
      const int bulkEnd = j & ~3;           // aligned bulk end (w>=33 -> >kA)
      int k4 = kA + 4 * lig;
      if (k4 < bulkEnd) {                   // double-buffered float4 bulk
        float4 a0 = *(const float4*)(ar + k4);
        float4 b0 = *(const float4*)(br + k4);
        for (k4 += 4 * G; k4 < bulkEnd; k4 += 4 * G) {
          float4 a1 = *(const float4*)(ar + k4);
          float4 b1 = *(const float4*)(br + k4);
          acc0 = fmaf(a0.x, b0.x, acc0);
          acc1 = fmaf(a0.y, b0.y, acc1);
          acc0 = fmaf(a0.z, b0.z, acc0);
          acc1 = fmaf(a0.w, b0.w, acc1);
          a0 = a1; b0 = b1;
        }
        acc0 = fmaf(a0.x, b0.x, acc0);
        acc1 = fmaf(a0.y, b0.y, acc1);
        acc0 = fmaf(a0.z, b0.z, acc0);
        acc1 = fmaf(a0.w, b0.w, acc1);
      }
      {
        const int k = bulkEnd + lig;        // tail peel (<=3 elems)
        if (k < j) acc0 = fmaf(ar[k], br[k], acc0);
      }
      float acc = acc0 + acc1;
#pragma unroll
      for (int o = G >> 1; o; o >>= 1) acc += __shfl_xor(acc, o, 64);
      if (lig == 0) {
        const float E = acc * __expf(sc[i * SL + j]);
        Eg[i * SL + j] = E;
        EgT[j * SL + i] = E;
        if (acc > 3.5e19f || acc < 3e-16f) red[fidx] = fmaxf(acc, 1e-30f);
      }
    }
    __syncthreads();
    const float fl = red[fidx];
    if (fl != 0.f) {                        // uniform, rare: re-center scale
      const float dc = (__logf(fl) + 8.0f) / (float)w;
      for (int t = tid; t < SL * SL; t += NT) {
        const int ii = t >> 8, jj = t & 255;
        const int wd = jj - ii;
        if (wd > 0 && wd <= w) {
          const float f = __expf(-dc * (float)wd);
          Eg[ii * SL + jj] *= f;
          EgT[jj * SL + ii] *= f;
        }
      }
      __syncthreads();
      if (tid == 0) red[fidx] = 0.f;
      __syncthreads();
    }
  }
}

// ---------------- outside: widths w0 down to w1 (gather, no atomics) -------
// g[p,q] = E_pq * (sum_{j>q} E[q,j]*H[p,j] + sum_{i<p} E[i,p]*H[i,q])
// H[p,q] = exp(sc[p,q]) * (that same sum). All four streams row-contiguous.
template <int G>
__device__ __forceinline__ void outsidePh(int w0, int w1, int tid,
    const float* __restrict__ sc, float* __restrict__ g,
    const float* __restrict__ Eg, const float* __restrict__ EgT,
    float* __restrict__ Hg, float* __restrict__ HgT) {
  constexpr int LG = (G == 4) ? 2 : (G == 8) ? 3 : (G == 16) ? 4 : (G == 32) ? 5 : 6;
  constexpr int NG = NT / G;
  const int c0 = tid >> LG;
  const int lig = tid & (G - 1);
  for (int w = w0; w >= w1; --w) {
    const int cells = SL - w;
    for (int c = c0; c < cells; c += NG) {
      const int p = c, q = p + w;
      const float Epq = Eg[p * SL + q];     // issue early; stale, off-chain
      float acc0 = 0.f, acc1 = 0.f;
      {  // right parents (p,j), j>q
        const float* er = Eg + q * SL;
        const float* hr = Hg + p * SL;
        const int jA = (q + 4) & ~3;
        {
          const int j = q + 1 + lig;        // front peel (<=3, j<=255 always)
          if (j < jA) acc0 = fmaf(er[j], hr[j], acc0);
        }
        int j4 = jA + 4 * lig;
        if (j4 < SL) {                      // aligned end: no tail
          float4 a0 = *(const float4*)(er + j4);
          float4 b0 = *(const float4*)(hr + j4);
          for (j4 += 4 * G; j4 < SL; j4 += 4 * G) {
            float4 a1 = *(const float4*)(er + j4);
            float4 b1 = *(const float4*)(hr + j4);
            acc0 = fmaf(a0.x, b0.x, acc0);
            acc1 = fmaf(a0.y, b0.y, acc1);
            acc0 = fmaf(a0.z, b0.z, acc0);
            acc1 = fmaf(a0.w, b0.w, acc1);
            a0 = a1; b0 = b1;
          }
          acc0 = fmaf(a0.x, b0.x, acc0);
          acc1 = fmaf(a0.y, b0.y, acc1);
          acc0 = fmaf(a0.z, b0.z, acc0);
          acc1 = fmaf(a0.w, b0.w, acc1);
        }
      }
      {  // left parents (i,q), i<p; overrun i in [p,p+2] safe: EgT[p][i>=p]=0
        const float* et = EgT + p * SL;
        const float* ht = HgT + q * SL;
        int i4 = 4 * lig;
        if (i4 < p) {
          float4 a0 = *(const float4*)(et + i4);
          float4 b0 = *(const float4*)(ht + i4);
          for (i4 += 4 * G; i4 < p; i4 += 4 * G) {
            float4 a1 = *(const float4*)(et + i4);
            float4 b1 = *(const float4*)(ht + i4);
            acc0 = fmaf(a0.x, b0.x, acc0);
            acc1 = fmaf(a0.y, b0.y, acc1);
            acc0 = fmaf(a0.z, b0.z, acc0);
            acc1 = fmaf(a0.w, b0.w, acc1);
            a0 = a1; b0 = b1;
          }
          acc0 = fmaf(a0.x, b0.x, acc0);
          acc1 = fmaf(a0.y, b0.y, acc1);
          acc0 = fmaf(a0.z, b0.z, acc0);
          acc1 = fmaf(a0.w, b0.w, acc1);
        }
      }
      float acc = acc0 + acc1;
#pragma unroll
      for (int o = G >> 1; o; o >>= 1) acc += __shfl_xor(acc, o, 64);
      if (lig == 0) {
        g[p * SL + q] = Epq * acc;
        const float H = acc * __expf(sc[p * SL + q]);
        Hg[p * SL + q] = H;
        HgT[q * SL + p] = H;
      }
    }
    __syncthreads();
  }
}

__global__ __launch_bounds__(NT) void cyk_v6(
    const float* __restrict__ scores, float* __restrict__ out,
    float* __restrict__ ws) {
  __shared__ float bandT[SL * BSTRIDE];     // phase-A log-scores, widths 1..34
  __shared__ float red[32];
  const int b = blockIdx.x;
  const int tid = threadIdx.x;
  const int lane = tid & 63;
  const int wave = tid >> 6;
  const size_t P = (size_t)SL * SL;
  const float* sc = scores + (size_t)b * P;
  float* g   = out + (size_t)b * P;
  float* Eg  = ws + (size_t)b * P;
  float* EgT = ws + (size_t)(BATCH + b) * P;
  float* Hg  = ws + (size_t)(2 * BATCH + b) * P;
  float* HgT = ws + (size_t)(3 * BATCH + b) * P;

  if (tid < 32) red[tid] = 0.f;
  // width 1: log-score = sc
  for (int i = tid; i < SL - 1; i += NT)
    bandT[i * BSTRIDE + 1] = sc[i * SL + i + 1];
  __syncthreads();

  // ---- phase A: widths 2..W0, log space in LDS band, G=4 ----
  {
    const int c4 = tid >> 2, lig = tid & 3;
    for (int w = 2; w <= W0; ++w) {
      if (c4 < SL - w) {
        const int i = c4, j = i + w;
        float m = -1e30f, sum = 0.f;
        int a1 = i * BSTRIDE + 1 + lig;                   // s[i][k]
        int a2 = (i + 1 + lig) * BSTRIDE + (w - 1 - lig); // s[k][j]
        for (int k = i + 1 + lig; k < j; k += 4) {
          const float t = bandT[a1] + bandT[a2];
          a1 += 4; a2 += 4 * BSTRIDE - 4;
          const float nm = fmaxf(m, t);
          sum = sum * __expf(m - nm) + __expf(t - nm);
          m = nm;
        }
#pragma unroll
        for (int o = 2; o; o >>= 1) {
          const float mo = __shfl_xor(m, o, 64);
          const float so = __shfl_xor(sum, o, 64);
          const float nm = fmaxf(m, mo);
          sum = sum * __expf(m - nm) + so * __expf(mo - nm);
          m = nm;
        }
        if (lig == 0) bandT[i * BSTRIDE + w] = sc[i * SL + j] + m + __logf(sum);
      }
      __syncthreads();
    }
  }

  // ---- calibrate slope c from width-W0 log-scores ----
  {
    const int idx = tid < SL - W0 ? tid : SL - W0 - 1;
    float v = bandT[idx * BSTRIDE + W0];
#pragma unroll
    for (int o = 32; o; o >>= 1) v = fmaxf(v, __shfl_xor(v, o, 64));
    if (lane == 0) red[wave] = v;
  }
  __syncthreads();
  float cc;
  {
    float mx = red[0];
#pragma unroll
    for (int t = 1; t < 16; ++t) mx = fmaxf(mx, red[t]);
    cc = mx / (float)W0;
  }
  __syncthreads();
  if (tid >= 16 && tid < 32) red[tid] = 0.f;   // clear flag slots

  // ---- convert widths 1..W0 to E-space mirrors ----
  for (int t = tid; t < W0 * SL; t += NT) {
    const int w = (t >> 8) + 1;
    const int i = t & 255;
    if (i < SL - w) {
      const float E = __expf(bandT[i * BSTRIDE + w] - cc * (float)w);
      Eg[i * SL + i + w] = E;
      EgT[(i + w) * SL + i] = E;
    }
  }
  __syncthreads();

  // ---- inside phase B ----
  insidePh<4>(W0 + 1, 95, tid, sc, Eg, EgT, red);
  insidePh<8>(96, 159, tid, sc, Eg, EgT, red);
  insidePh<16>(160, 223, tid, sc, Eg, EgT, red);
  insidePh<32>(224, 247, tid, sc, Eg, EgT, red);
  insidePh<64>(248, 255, tid, sc, Eg, EgT, red);

  // ---- root ----
  if (tid == 0) {
    g[0 * SL + (SL - 1)] = 1.0f;
    const float Er = Eg[0 * SL + (SL - 1)];
    const float Hr = (Er > 0.f) ? __expf(sc[0 * SL + (SL - 1)]) / Er : 0.f;
    Hg[0 * SL + (SL - 1)] = Hr;
    HgT[(SL - 1) * SL + 0] = Hr;
  }
  __syncthreads();

  // ---- outside ----
  outsidePh<64>(254, 248, tid, sc, g, Eg, EgT, Hg, HgT);
  outsidePh<32>(247, 224, tid, sc, g, Eg, EgT, Hg, HgT);
  outsidePh<16>(223, 160, tid, sc, g, Eg, EgT, Hg, HgT);
  outsidePh<8>(159, 96, tid, sc, g, Eg, EgT, Hg, HgT);
  outsidePh<4>(95, 33, tid, sc, g, Eg, EgT, Hg, HgT);
  outsidePh<4>(32, 1, tid, sc, g, Eg, EgT, Hg, HgT);
}

// ---------------- fallback: proven global-memory kernel ----------------
__device__ __forceinline__ float grpMaxR(float v, int G) {
#pragma unroll
  for (int o = 32; o; o >>= 1)
    if (o < G) v = fmaxf(v, __shfl_xor(v, o, 64));
  return v;
}
__device__ __forceinline__ float grpSumR(float v, int G) {
#pragma unroll
  for (int o = 32; o; o >>= 1)
    if (o < G) v += __shfl_xor(v, o, 64);
  return v;
}

__global__ __launch_bounds__(NT) void cyk_io_fb(
    const float* __restrict__ scores, float* __restrict__ out,
    float* __restrict__ ws) {
  const int b = blockIdx.x;
  const int tid = threadIdx.x;
  const size_t P = (size_t)SL * SL;
  const float* sc = scores + (size_t)b * P;
  float* g = out + (size_t)b * P;
  float* s = ws + (size_t)b * P;
  float* l = ws + (size_t)(BATCH + b) * P;

  for (int i = tid; i < SL - 1; i += NT) {
    s[i * SL + i + 1] = sc[i * SL + i + 1];
    l[i * SL + i + 1] = 0.f;
  }
  __syncthreads();
  for (int w = 2; w < SL; ++w) {
    const int cells = SL - w;
    int G = NT / cells;
    G = (G >= 64) ? 64 : (1 << (31 - __clz(G)));
    const int lg = 31 - __clz(G);
    const int c = tid >> lg;
    const int lig = tid & (G - 1);
    if (c < cells) {
      const int i = c, j = i + w;
      const float* srow = s + i * SL;
      float m = -INFINITY;
      for (int k = i + 1 + lig; k < j; k += G)
        m = fmaxf(m, srow[k] + s[k * SL + j]);
      m = grpMaxR(m, G);
      float sum = 0.f;
      for (int k = i + 1 + lig; k < j; k += G)
        sum += __expf(srow[k] + s[k * SL + j] - m);
      sum = grpSumR(sum, G);
      if (lig == 0) {
        const float lse = m + __logf(sum);
        s[i * SL + j] = sc[i * SL + j] + lse;
        l[i * SL + j] = lse;
      }
    }
    __syncthreads();
  }
  if (tid == 0) g[0 * SL + (SL - 1)] = 1.0f;
  __syncthreads();
  for (int w = SL - 2; w >= 1; --w) {
    const int cells = SL - w;
    int G = NT / cells;
    G = (G >= 64) ? 64 : (1 << (31 - __clz(G)));
    const int lg = 31 - __clz(G);
    const int c = tid >> lg;
    const int lig = tid & (G - 1);
    if (c < cells) {
      const int p = c, q = p + w;
      const float spq = s[p * SL + q];
      const int TR = SL - 1 - q;
      const int T = TR + p;
      float acc = 0.f;
      for (int t = lig; t < T; t += G) {
        if (t < TR) {
          const int j = q + 1 + t;
          acc += g[p * SL + j] * __expf(spq + s[q * SL + j] - l[p * SL + j]);
        } else {
          const int i = t - TR;
          acc += g[i * SL + q] * __expf(s[i * SL + p] + spq - l[i * SL + q]);
        }
      }
      acc = grpSumR(acc, G);
      if (lig == 0) g[p * SL + q] = acc;
    }
    __syncthreads();
  }
}

extern "C" void kernel_launch(void* const* d_in, const int* in_sizes, int n_in,
                              void* d_out, int out_size, void* d_ws, size_t ws_size,
                              hipStream_t stream) {
  const float* scores = (const float*)d_in[0];
  // d_in[1] = mask: triu(k=1) broadcast -> lens == SL-1 always; unused.
  float* out = (float*)d_out;
  float* ws = (float*)d_ws;

  const size_t sq = (size_t)SL * SL * sizeof(float);   // 256 KB
  hipMemsetAsync(d_out, 0, (size_t)BATCH * sq, stream);

  if (ws_size >= (size_t)4 * BATCH * sq) {
    hipMemsetAsync(ws, 0, (size_t)4 * BATCH * sq, stream);  // zero guards
    cyk_v6<<<BATCH, NT, 0, stream>>>(scores, out, ws);
  } else {
    cyk_io_fb<<<BATCH, NT, 0, stream>>>(scores, out, ws);
  }
}

// Round 7
// 1174.602 us; speedup vs baseline: 1.1693x; 1.1693x over previous
//
#include <hip/hip_runtime.h>

#define SL 256
#define BATCH 8
#define NT 1024
#define W0 32
#define TRIF 33152                       // padded packed triangle (floats)
#define LDSB ((TRIF + 32 + 256 + 512 + 256) * 4)   // 136,832 B

// Packed-column triangle: column j (cells (k,j), k=0..j-1) contiguous.
// Columns j and 256-j share a 260-float slot; every base 16B-aligned.
__device__ __forceinline__ int colOff(int j) {
  if (j <= 127) return (j - 1) * 260;
  if (j == 128) return 127 * 260;
  int jp = 256 - j;
  return (jp - 1) * 260 + ((jp + 3) & ~3);
}

template <int G> struct LgOf { static constexpr int v = (G==4)?2:(G==8)?3:(G==16)?4:(G==32)?5:6; };

template <int G>
__device__ __forceinline__ float grpSum(float v) {
#pragma unroll
  for (int o = G >> 1; o; o >>= 1) v += __shfl_xor(v, o, 64);
  return v;
}

// Per-lane partial dot for inside cell (i,j): k in [i+2, j-2] STRICT
// (boundary terms k=i+1, k=j-1 added at finalize). Requires j-i >= 33
// so hi > lo (no peel overlap). Eg row = global float4; tri col = LDS b128.
template <int G>
__device__ __forceinline__ float inPartial(int i, int j, int lig,
    const float* __restrict__ Eg, const float* __restrict__ tri) {
  const float* ar = Eg + i * SL;
  const float* bc = tri + colOff(j);
  float a0 = 0.f, a1 = 0.f;
  const int lo = (i + 5) & ~3;           // align4up(i+2)
  const int hi = (j - 1) & ~3;           // align4dn(j-1), exclusive bulk end
  { const int k = i + 2 + lig; if (k < lo) a0 = fmaf(ar[k], bc[k], a0); }
  for (int k4 = lo + 4 * lig; k4 < hi; k4 += 4 * G) {
    float4 a = *(const float4*)(ar + k4);
    float4 b = *(const float4*)(bc + k4);
    a0 = fmaf(a.x, b.x, a0); a1 = fmaf(a.y, b.y, a1);
    a0 = fmaf(a.z, b.z, a0); a1 = fmaf(a.w, b.w, a1);
  }
  { const int k = hi + lig; if (k <= j - 2) a0 = fmaf(ar[k], bc[k], a0); }
  return a0 + a1;
}

// Per-lane partial for outside cell (p,q): right parents j in [q+2,255],
// left parents i in [0,p-2] STRICT (width w+1 boundary added at finalize).
template <int G>
__device__ __forceinline__ float outPartial(int p, int q, int lig,
    const float* __restrict__ Eg, const float* __restrict__ tri,
    const float* __restrict__ Hg, const float* __restrict__ HgT) {
  float a0 = 0.f, a1 = 0.f;
  if (q <= SL - 3) {
    const float* er = Eg + q * SL;
    const float* hr = Hg + p * SL;
    const int lo = (q + 5) & ~3;         // align4up(q+2)
    { const int j = q + 2 + lig; if (j < lo && j < SL) a0 = fmaf(er[j], hr[j], a0); }
    for (int j4 = lo + 4 * lig; j4 < SL; j4 += 4 * G) {
      float4 a = *(const float4*)(er + j4);
      float4 b = *(const float4*)(hr + j4);
      a0 = fmaf(a.x, b.x, a0); a1 = fmaf(a.y, b.y, a1);
      a0 = fmaf(a.z, b.z, a0); a1 = fmaf(a.w, b.w, a1);
    }
  }
  if (p >= 2) {
    const float* et = tri + colOff(p);   // E[i,p], contiguous in i (LDS)
    const float* ht = HgT + q * SL;
    const int hi = (p - 1) & ~3;         // align4dn(p-1)
    for (int i4 = 4 * lig; i4 < hi; i4 += 4 * G) {
      float4 a = *(const float4*)(et + i4);
      float4 b = *(const float4*)(ht + i4);
      a0 = fmaf(a.x, b.x, a0); a1 = fmaf(a.y, b.y, a1);
      a0 = fmaf(a.z, b.z, a0); a1 = fmaf(a.w, b.w, a1);
    }
    { const int i = hi + lig; if (i <= p - 2) a0 = fmaf(et[i], ht[i], a0); }
  }
  return a0 + a1;
}

// Pipelined inside: finalize diag w (O(1) LDS chain) + compute partial for w+1.
template <int G>
__device__ void pipeIn(int w0, int w1, int tid, const float* __restrict__ sc,
    float* __restrict__ Eg, float* __restrict__ tri, float* __restrict__ W1a,
    float* __restrict__ ring, float* __restrict__ Pd, float* __restrict__ red) {
  constexpr int LG = LgOf<G>::v;
  constexpr int NG = NT / G;
  const int c0 = tid >> LG;
  const int lig = tid & (G - 1);
  for (int w = w0; w <= w1; ++w) {
    const int cells = SL - w;
    const int fidx = 16 + (w & 1);
    const float* rPrev = ring + ((w - 1) & 1) * SL;   // diag w-1 values
    float* rCur = ring + (w & 1) * SL;
    for (int c = c0; c < cells; c += NG) {
      const int i = c, j = i + w;
      const float acc = Pd[c] + W1a[i] * rPrev[i + 1] + rPrev[i] * W1a[j - 1];
      const float E = acc * __expf(sc[i * SL + j]);
      if (lig == 0) {
        tri[colOff(j) + i] = E;
        Eg[i * SL + j] = E;
        rCur[i] = E;
        if (acc > 3.5e19f || acc < 3e-16f) red[fidx] = fmaxf(acc, 1e-30f);
      }
    }
    if (w < SL - 1) {
      const int cellsP = cells - 1;
      for (int c = c0; c < cellsP; c += NG) {
        float part = inPartial<G>(c, c + w + 1, lig, Eg, tri);
        part = grpSum<G>(part);
        if (lig == 0) Pd[c] = part;
      }
    }
    __syncthreads();
    const float fl = red[fidx];
    if (fl != 0.f) {                      // rare uniform rescale: re-center scale
      const float dc = (__logf(fl) + 8.0f) / (float)w;
      for (int j = 1 + (tid >> 6); j < SL; j += 16) {
        const int base = colOff(j);
        for (int k = (tid & 63); k < j; k += 64)
          tri[base + k] *= __expf(-dc * (float)(j - k));
      }
      for (int t = tid; t < SL * SL; t += NT) {
        const int wd = (t & 255) - (t >> 8);
        if (wd > 0 && wd <= w) Eg[t] *= __expf(-dc * (float)wd);
      }
      if (tid < SL - 1) W1a[tid] *= __expf(-dc);
      if (tid < SL - w) rCur[tid] *= __expf(-dc * (float)w);
      if (w < SL - 1 && tid < SL - w - 1) Pd[tid] *= __expf(-dc * (float)(w + 1));
      __syncthreads();
      if (tid == 0) red[fidx] = 0.f;
      __syncthreads();
    }
  }
}

// Pipelined outside: finalize diag w + partial for w-1.
template <int G>
__device__ void pipeOut(int w0, int w1, int tid, const float* __restrict__ sc,
    float* __restrict__ g, const float* __restrict__ Eg,
    const float* __restrict__ tri, const float* __restrict__ W1a,
    float* __restrict__ Hg, float* __restrict__ HgT,
    float* __restrict__ ring, float* __restrict__ Pd) {
  constexpr int LG = LgOf<G>::v;
  constexpr int NG = NT / G;
  const int c0 = tid >> LG;
  const int lig = tid & (G - 1);
  for (int w = w0; w >= w1; --w) {
    const int cells = SL - w;
    const float* rPrev = ring + ((w + 1) & 1) * SL;   // diag w+1 H values
    float* rCur = ring + (w & 1) * SL;
    for (int c = c0; c < cells; c += NG) {
      const int p = c, q = p + w;
      float acc = Pd[c];
      if (q <= SL - 2) acc = fmaf(W1a[q], rPrev[p], acc);       // parent (p,q+1)
      if (p >= 1) acc = fmaf(W1a[p - 1], rPrev[p - 1], acc);    // parent (p-1,q)
      const float gv = tri[colOff(q) + p] * acc;
      const float H = acc * __expf(sc[p * SL + q]);
      if (lig == 0) {
        g[p * SL + q] = gv;
        Hg[p * SL + q] = H;
        HgT[q * SL + p] = H;
        rCur[p] = H;
      }
    }
    if (w > 1) {
      const int cellsP = cells + 1;
      for (int c = c0; c < cellsP; c += NG) {
        float part = outPartial<G>(c, c + w - 1, lig, Eg, tri, Hg, HgT);
        part = grpSum<G>(part);
        if (lig == 0) Pd[c] = part;
      }
    }
    __syncthreads();
  }
}

__global__ __launch_bounds__(NT) void cyk_v7(
    const float* __restrict__ scores, float* __restrict__ out,
    float* __restrict__ ws) {
  extern __shared__ float sh[];
  float* tri  = sh;            // packed E triangle (phase A: log scores)
  float* red  = sh + TRIF;     // [0:16) calib, 16/17 overflow flags
  float* W1a  = red + 32;      // width-1 E values
  float* ring = W1a + 256;     // 2 x 256 ping-pong prev-diagonal values
  float* Pd   = ring + 512;    // per-cell pipelined partial sums
  const int b = blockIdx.x;
  const int tid = threadIdx.x;
  const int lane = tid & 63;
  const int wave = tid >> 6;
  const size_t P = (size_t)SL * SL;
  const float* sc = scores + (size_t)b * P;
  float* g   = out + (size_t)b * P;
  float* Eg  = ws + (size_t)b * P;
  float* Hg  = ws + (size_t)(BATCH + b) * P;
  float* HgT = ws + (size_t)(2 * BATCH + b) * P;

  for (int t = tid; t < TRIF; t += NT) tri[t] = 0.f;
  if (tid < 32) red[tid] = 0.f;
  __syncthreads();

  for (int i = tid; i < SL - 1; i += NT)       // width 1 log-scores
    tri[colOff(i + 1) + i] = sc[i * SL + i + 1];
  __syncthreads();

  // ---- phase A: widths 2..W0, log space, G=4 ----
  {
    const int c4 = tid >> 2, lig = tid & 3;
    for (int w = 2; w <= W0; ++w) {
      if (c4 < SL - w) {
        const int i = c4, j = i + w;
        const int oj = colOff(j);
        float m = -1e30f, sum = 0.f;
        for (int k = i + 1 + lig; k < j; k += 4) {
          const float t = tri[colOff(k) + i] + tri[oj + k];
          const float nm = fmaxf(m, t);
          sum = sum * __expf(m - nm) + __expf(t - nm);
          m = nm;
        }
#pragma unroll
        for (int o = 2; o; o >>= 1) {
          const float mo = __shfl_xor(m, o, 64);
          const float so = __shfl_xor(sum, o, 64);
          const float nm = fmaxf(m, mo);
          sum = sum * __expf(m - nm) + so * __expf(mo - nm);
          m = nm;
        }
        if (lig == 0) tri[oj + i] = sc[i * SL + j] + m + __logf(sum);
      }
      __syncthreads();
    }
  }

  // ---- calibrate slope cc from width-W0 log-scores ----
  {
    const int idx = tid < SL - W0 ? tid : SL - W0 - 1;
    float v = tri[colOff(idx + W0) + idx];
#pragma unroll
    for (int o = 32; o; o >>= 1) v = fmaxf(v, __shfl_xor(v, o, 64));
    if (lane == 0) red[wave] = v;
  }
  __syncthreads();
  float cc;
  {
    float mx = red[0];
#pragma unroll
    for (int t = 1; t < 16; ++t) mx = fmaxf(mx, red[t]);
    cc = mx / (float)W0;
  }
  __syncthreads();

  // ---- convert widths 1..W0 to E-space; seed W1a + ring[0] (width W0) ----
  for (int t = tid; t < W0 * SL; t += NT) {
    const int w = (t >> 8) + 1;
    const int i = t & 255;
    if (i < SL - w) {
      const int o = colOff(i + w) + i;
      const float E = __expf(tri[o] - cc * (float)w);
      tri[o] = E;
      Eg[i * SL + i + w] = E;
      if (w == 1) W1a[i] = E;
      if (w == W0) ring[0 * SL + i] = E;   // W0&1 == 0
    }
  }
  __syncthreads();

  // ---- prologue: Pd for w = W0+1 ----
  {
    const int c0 = tid >> 2, lig = tid & 3;
    for (int c = c0; c < SL - (W0 + 1); c += 256) {
      float part = inPartial<4>(c, c + W0 + 1, lig, Eg, tri);
      part = grpSum<4>(part);
      if (lig == 0) Pd[c] = part;
    }
  }
  __syncthreads();

  pipeIn<4>(33, 127, tid, sc, Eg, tri, W1a, ring, Pd, red);
  pipeIn<8>(128, 191, tid, sc, Eg, tri, W1a, ring, Pd, red);
  pipeIn<16>(192, 223, tid, sc, Eg, tri, W1a, ring, Pd, red);
  pipeIn<32>(224, 239, tid, sc, Eg, tri, W1a, ring, Pd, red);
  pipeIn<64>(240, 255, tid, sc, Eg, tri, W1a, ring, Pd, red);

  // ---- outside prologue: root + zero partials ----
  if (tid < 256) Pd[tid] = 0.f;
  if (tid == 0) {
    g[0 * SL + (SL - 1)] = 1.0f;
    const float Er = tri[colOff(SL - 1) + 0];
    const float Hr = (Er > 0.f) ? __expf(sc[SL - 1]) / Er : 0.f;
    Hg[0 * SL + (SL - 1)] = Hr;
    HgT[(SL - 1) * SL + 0] = Hr;
    ring[1 * SL + 0] = Hr;               // 255&1 == 1
  }
  __syncthreads();

  pipeOut<64>(254, 240, tid, sc, g, Eg, tri, W1a, Hg, HgT, ring, Pd);
  pipeOut<32>(239, 224, tid, sc, g, Eg, tri, W1a, Hg, HgT, ring, Pd);
  pipeOut<16>(223, 192, tid, sc, g, Eg, tri, W1a, Hg, HgT, ring, Pd);
  pipeOut<8>(191, 128, tid, sc, g, Eg, tri, W1a, Hg, HgT, ring, Pd);
  pipeOut<4>(127, 1, tid, sc, g, Eg, tri, W1a, Hg, HgT, ring, Pd);
}

// ---------------- fallback: proven global-memory kernel ----------------
__device__ __forceinline__ float grpMaxR(float v, int G) {
#pragma unroll
  for (int o = 32; o; o >>= 1)
    if (o < G) v = fmaxf(v, __shfl_xor(v, o, 64));
  return v;
}
__device__ __forceinline__ float grpSumR(float v, int G) {
#pragma unroll
  for (int o = 32; o; o >>= 1)
    if (o < G) v += __shfl_xor(v, o, 64);
  return v;
}

__global__ __launch_bounds__(NT) void cyk_io_fb(
    const float* __restrict__ scores, float* __restrict__ out,
    float* __restrict__ ws) {
  const int b = blockIdx.x;
  const int tid = threadIdx.x;
  const size_t P = (size_t)SL * SL;
  const float* sc = scores + (size_t)b * P;
  float* g = out + (size_t)b * P;
  float* s = ws + (size_t)b * P;
  float* l = ws + (size_t)(BATCH + b) * P;

  for (int i = tid; i < SL - 1; i += NT) {
    s[i * SL + i + 1] = sc[i * SL + i + 1];
    l[i * SL + i + 1] = 0.f;
  }
  __syncthreads();
  for (int w = 2; w < SL; ++w) {
    const int cells = SL - w;
    int G = NT / cells;
    G = (G >= 64) ? 64 : (1 << (31 - __clz(G)));
    const int lg = 31 - __clz(G);
    const int c = tid >> lg;
    const int lig = tid & (G - 1);
    if (c < cells) {
      const int i = c, j = i + w;
      const float* srow = s + i * SL;
      float m = -INFINITY;
      for (int k = i + 1 + lig; k < j; k += G)
        m = fmaxf(m, srow[k] + s[k * SL + j]);
      m = grpMaxR(m, G);
      float sum = 0.f;
      for (int k = i + 1 + lig; k < j; k += G)
        sum += __expf(srow[k] + s[k * SL + j] - m);
      sum = grpSumR(sum, G);
      if (lig == 0) {
        const float lse = m + __logf(sum);
        s[i * SL + j] = sc[i * SL + j] + lse;
        l[i * SL + j] = lse;
      }
    }
    __syncthreads();
  }
  if (tid == 0) g[0 * SL + (SL - 1)] = 1.0f;
  __syncthreads();
  for (int w = SL - 2; w >= 1; --w) {
    const int cells = SL - w;
    int G = NT / cells;
    G = (G >= 64) ? 64 : (1 << (31 - __clz(G)));
    const int lg = 31 - __clz(G);
    const int c = tid >> lg;
    const int lig = tid & (G - 1);
    if (c < cells) {
      const int p = c, q = p + w;
      const float spq = s[p * SL + q];
      const int TR = SL - 1 - q;
      const int T = TR + p;
      float acc = 0.f;
      for (int t = lig; t < T; t += G) {
        if (t < TR) {
          const int j = q + 1 + t;
          acc += g[p * SL + j] * __expf(spq + s[q * SL + j] - l[p * SL + j]);
        } else {
          const int i = t - TR;
          acc += g[i * SL + q] * __expf(s[i * SL + p] + spq - l[i * SL + q]);
        }
      }
      acc = grpSumR(acc, G);
      if (lig == 0) g[p * SL + q] = acc;
    }
    __syncthreads();
  }
}

extern "C" void kernel_launch(void* const* d_in, const int* in_sizes, int n_in,
                              void* d_out, int out_size, void* d_ws, size_t ws_size,
                              hipStream_t stream) {
  const float* scores = (const float*)d_in[0];
  // d_in[1] = mask: triu(k=1) broadcast -> lens == SL-1 always; unused.
  float* out = (float*)d_out;
  float* ws = (float*)d_ws;

  const size_t sq = (size_t)SL * SL * sizeof(float);   // 256 KB
  hipMemsetAsync(d_out, 0, (size_t)BATCH * sq, stream);

  int dev = 0;
  hipGetDevice(&dev);
  int maxShm = 0;
  hipDeviceGetAttribute(&maxShm, hipDeviceAttributeMaxSharedMemoryPerBlock, dev);
  (void)hipFuncSetAttribute(reinterpret_cast<const void*>(cyk_v7),
                            hipFuncAttributeMaxDynamicSharedMemorySize, LDSB);

  if (maxShm >= LDSB && ws_size >= (size_t)3 * BATCH * sq) {
    hipMemsetAsync(ws, 0, (size_t)3 * BATCH * sq, stream);  // zero guards
    cyk_v7<<<BATCH, NT, LDSB, stream>>>(scores, out, ws);
  } else {
    cyk_io_fb<<<BATCH, NT, 0, stream>>>(scores, out, ws);
  }
}

// Round 9
// 1027.931 us; speedup vs baseline: 1.3362x; 1.1427x over previous
//
#include <hip/hip_runtime.h>

#define SL 256
#define BATCH 8
#define NT 1024
#define W0 32
#define LDSF 33152                 // padded packed triangle (floats), 16B-aligned rows
#define REDF 32
#define LDSB ((LDSF + REDF) * 4)   // 132,736 B dynamic LDS

// Row j (j in [1,255], holding cells (k,j), k=0..j-1) packed: rows j and 256-j
// share a 260-float slot; every row base is 16B-aligned.
__device__ __forceinline__ int rowOff(int j) {
  if (j <= 127) return (j - 1) * 260;
  if (j == 128) return 127 * 260;
  int jp = 256 - j;                       // 1..127
  return (jp - 1) * 260 + ((jp + 3) & ~3);
}

template <int G>
__device__ __forceinline__ float grpSum(float v) {
#pragma unroll
  for (int o = G >> 1; o; o >>= 1) v += __shfl_xor(v, o, 64);
  return v;
}

// Rescale E tables by exp(-dc*width) for all computed widths <= wcur.
__device__ void rescaleE(int tid, float dc, int wcur, float* Eg, float* sh) {
  const int lane = tid & 63, wave = tid >> 6;
  for (int j = 1 + wave; j < SL; j += 16) {
    int jlo = j - wcur; if (jlo < 0) jlo = 0;
    int base = rowOff(j);
    for (int i = jlo + lane; i < j; i += 64)
      sh[base + i] *= __expf(-dc * (float)(j - i));
  }
  for (int idx = tid; idx < SL * SL; idx += NT) {
    int i = idx >> 8, j = idx & 255;
    int wd = j - i;
    if (wd > 0 && wd <= wcur) Eg[idx] *= __expf(-dc * (float)wd);
  }
}

// Inside widths [w0,w1]: R = sum_k E[i,k]*E[k,j]; E_cell = R*exp(sc).
// v9: identical address set to v5; loads batched 4 chunks deep (8 independent
// loads in flight before any fma) + remainder loop.
template <int G>
__device__ __forceinline__ void insideB(int w0, int w1, int tid,
    const float* __restrict__ sc, float* __restrict__ Eg,
    float* __restrict__ sh, float* __restrict__ red) {
  constexpr int LG = (G == 4) ? 2 : (G == 8) ? 3 : (G == 16) ? 4 : (G == 32) ? 5 : 6;
  constexpr int STEP = 4 * G;
  const int c = tid >> LG, lig = tid & (G - 1);
  for (int w = w0; w <= w1; ++w) {
    const int fidx = 16 + (w & 1);        // ping-pong flag slot (race-free read)
    if (c < SL - w) {
      const int i = c, j = i + w;
      const int oj = rowOff(j);
      const float* er = Eg + i * SL;      // global, coalesced
      const float* bs = sh + oj;          // LDS, contiguous
      float a0 = 0.f, a1 = 0.f, a2 = 0.f, a3 = 0.f;
      int s4 = ((i + 1) & ~3) + 4 * lig;
      for (; s4 + 3 * STEP < j; s4 += 4 * STEP) {
        float4 A0 = *(const float4*)(er + s4);
        float4 A1 = *(const float4*)(er + s4 + STEP);
        float4 A2 = *(const float4*)(er + s4 + 2 * STEP);
        float4 A3 = *(const float4*)(er + s4 + 3 * STEP);
        float4 B0 = *(const float4*)(bs + s4);
        float4 B1 = *(const float4*)(bs + s4 + STEP);
        float4 B2 = *(const float4*)(bs + s4 + 2 * STEP);
        float4 B3 = *(const float4*)(bs + s4 + 3 * STEP);
        a0 = fmaf(A0.x, B0.x, a0); a1 = fmaf(A0.y, B0.y, a1);
        a2 = fmaf(A0.z, B0.z, a2); a3 = fmaf(A0.w, B0.w, a3);
        a0 = fmaf(A1.x, B1.x, a0); a1 = fmaf(A1.y, B1.y, a1);
        a2 = fmaf(A1.z, B1.z, a2); a3 = fmaf(A1.w, B1.w, a3);
        a0 = fmaf(A2.x, B2.x, a0); a1 = fmaf(A2.y, B2.y, a1);
        a2 = fmaf(A2.z, B2.z, a2); a3 = fmaf(A2.w, B2.w, a3);
        a0 = fmaf(A3.x, B3.x, a0); a1 = fmaf(A3.y, B3.y, a1);
        a2 = fmaf(A3.z, B3.z, a2); a3 = fmaf(A3.w, B3.w, a3);
      }
      for (; s4 < j; s4 += STEP) {
        float4 A = *(const float4*)(er + s4);
        float4 B = *(const float4*)(bs + s4);
        a0 = fmaf(A.x, B.x, a0); a1 = fmaf(A.y, B.y, a1);
        a2 = fmaf(A.z, B.z, a2); a3 = fmaf(A.w, B.w, a3);
      }
      float acc = grpSum<G>((a0 + a1) + (a2 + a3));
      if (lig == 0) {
        float E = acc * __expf(sc[i * SL + j]);
        sh[oj + i] = E;
        Eg[i * SL + j] = E;
        if (acc > 3.5e19f || acc < 3e-16f) red[fidx] = fmaxf(acc, 1e-30f);
      }
    }
    __syncthreads();
    float fl = red[fidx];
    if (fl != 0.f) {                      // uniform branch, rare
      float dc = (__logf(fl) + 8.0f) / (float)w;   // recenter dev to ~-8
      rescaleE(tid, dc, w, Eg, sh);
      __syncthreads();
      if (tid == 0) red[fidx] = 0.f;
      __syncthreads();
    }
  }
}

// Outside widths w0 down to w1 (gather): g = E_pq*(sum E[q,j]H[p,j] + sum E[i,p]H[i,q]).
// v9: same addresses as v5, batched loads + remainder.
template <int G>
__device__ __forceinline__ void outsideB(int w0, int w1, int tid,
    const float* __restrict__ sc, float* __restrict__ gOut,
    const float* __restrict__ Eg, float* __restrict__ Hg,
    float* __restrict__ HTg, const float* __restrict__ sh) {
  constexpr int LG = (G == 4) ? 2 : (G == 8) ? 3 : (G == 16) ? 4 : (G == 32) ? 5 : 6;
  constexpr int STEP = 4 * G;
  const int c = tid >> LG, lig = tid & (G - 1);
  for (int w = w0; w >= w1; --w) {
    if (c < SL - w) {
      const int p = c, q = p + w;
      float a0 = 0.f, a1 = 0.f, a2 = 0.f, a3 = 0.f;
      {  // right parents (p,j), j>q
        const float* er = Eg + q * SL;
        const float* hr = Hg + p * SL;
        int s4 = ((q + 1) & ~3) + 4 * lig;
        for (; s4 + 3 * STEP < SL; s4 += 4 * STEP) {
          float4 A0 = *(const float4*)(er + s4);
          float4 A1 = *(const float4*)(er + s4 + STEP);
          float4 A2 = *(const float4*)(er + s4 + 2 * STEP);
          float4 A3 = *(const float4*)(er + s4 + 3 * STEP);
          float4 B0 = *(const float4*)(hr + s4);
          float4 B1 = *(const float4*)(hr + s4 + STEP);
          float4 B2 = *(const float4*)(hr + s4 + 2 * STEP);
          float4 B3 = *(const float4*)(hr + s4 + 3 * STEP);
          a0 = fmaf(A0.x, B0.x, a0); a1 = fmaf(A0.y, B0.y, a1);
          a2 = fmaf(A0.z, B0.z, a2); a3 = fmaf(A0.w, B0.w, a3);
          a0 = fmaf(A1.x, B1.x, a0); a1 = fmaf(A1.y, B1.y, a1);
          a2 = fmaf(A1.z, B1.z, a2); a3 = fmaf(A1.w, B1.w, a3);
          a0 = fmaf(A2.x, B2.x, a0); a1 = fmaf(A2.y, B2.y, a1);
          a2 = fmaf(A2.z, B2.z, a2); a3 = fmaf(A2.w, B2.w, a3);
          a0 = fmaf(A3.x, B3.x, a0); a1 = fmaf(A3.y, B3.y, a1);
          a2 = fmaf(A3.z, B3.z, a2); a3 = fmaf(A3.w, B3.w, a3);
        }
        for (; s4 < SL; s4 += STEP) {
          float4 A = *(const float4*)(er + s4);
          float4 B = *(const float4*)(hr + s4);
          a0 = fmaf(A.x, B.x, a0); a1 = fmaf(A.y, B.y, a1);
          a2 = fmaf(A.z, B.z, a2); a3 = fmaf(A.w, B.w, a3);
        }
      }
      if (p > 0) {                        // left parents (i,q), i<p
        const float* et = sh + rowOff(p); // E column p == LDS row p
        const float* ht = HTg + q * SL;
        int s4 = 4 * lig;
        for (; s4 + 3 * STEP < p; s4 += 4 * STEP) {
          float4 A0 = *(const float4*)(et + s4);
          float4 A1 = *(const float4*)(et + s4 + STEP);
          float4 A2 = *(const float4*)(et + s4 + 2 * STEP);
          float4 A3 = *(const float4*)(et + s4 + 3 * STEP);
          float4 B0 = *(const float4*)(ht + s4);
          float4 B1 = *(const float4*)(ht + s4 + STEP);
          float4 B2 = *(const float4*)(ht + s4 + 2 * STEP);
          float4 B3 = *(const float4*)(ht + s4 + 3 * STEP);
          a0 = fmaf(A0.x, B0.x, a0); a1 = fmaf(A0.y, B0.y, a1);
          a2 = fmaf(A0.z, B0.z, a2); a3 = fmaf(A0.w, B0.w, a3);
          a0 = fmaf(A1.x, B1.x, a0); a1 = fmaf(A1.y, B1.y, a1);
          a2 = fmaf(A1.z, B1.z, a2); a3 = fmaf(A1.w, B1.w, a3);
          a0 = fmaf(A2.x, B2.x, a0); a1 = fmaf(A2.y, B2.y, a1);
          a2 = fmaf(A2.z, B2.z, a2); a3 = fmaf(A2.w, B2.w, a3);
          a0 = fmaf(A3.x, B3.x, a0); a1 = fmaf(A3.y, B3.y, a1);
          a2 = fmaf(A3.z, B3.z, a2); a3 = fmaf(A3.w, B3.w, a3);
        }
        for (; s4 < p; s4 += STEP) {
          float4 A = *(const float4*)(et + s4);
          float4 B = *(const float4*)(ht + s4);
          a0 = fmaf(A.x, B.x, a0); a1 = fmaf(A.y, B.y, a1);
          a2 = fmaf(A.z, B.z, a2); a3 = fmaf(A.w, B.w, a3);
        }
      }
      float acc = grpSum<G>((a0 + a1) + (a2 + a3));
      if (lig == 0) {
        float Epq = sh[rowOff(q) + p];
        gOut[p * SL + q] = Epq * acc;
        float H = acc * __expf(sc[p * SL + q]);
        Hg[p * SL + q] = H;
        HTg[q * SL + p] = H;
      }
    }
    __syncthreads();
  }
}

__global__ __launch_bounds__(NT) void cyk_exp(
    const float* __restrict__ scores, float* __restrict__ out,
    float* __restrict__ ws) {
  extern __shared__ float sh[];
  float* red = sh + LDSF;
  const int b = blockIdx.x;
  const int tid = threadIdx.x;
  const int lane = tid & 63;
  const int wave = tid >> 6;
  const size_t P = (size_t)SL * SL;
  const float* sc = scores + (size_t)b * P;
  float* g   = out + (size_t)b * P;
  float* Eg  = ws + (size_t)b * P;                 // E, row-major (lower tri = 0)
  float* Hg  = ws + (size_t)(BATCH + b) * P;       // H, row-major
  float* HTg = ws + (size_t)(2 * BATCH + b) * P;   // H transposed

  for (int idx = tid; idx < LDSF; idx += NT) sh[idx] = 0.f;
  if (tid < REDF) red[tid] = 0.f;
  __syncthreads();

  // width 1: store s = sc (log space for phase A)
  for (int i = tid; i < SL - 1; i += NT)
    sh[rowOff(i + 1) + i] = sc[i * SL + i + 1];
  __syncthreads();

  // ---- phase A: widths 2..W0, log space (exp per term; only ~4% of terms) ----
  {
    const int c4 = tid >> 2, lig = tid & 3;
    for (int w = 2; w <= W0; ++w) {
      if (c4 < SL - w) {
        const int i = c4, j = i + w;
        const int oj = rowOff(j);
        float m = -1e30f, sum = 0.f;
        for (int k = i + 1 + lig; k < j; k += 4) {
          float t = sh[rowOff(k) + i] + sh[oj + k];
          float nm = fmaxf(m, t);
          sum = sum * __expf(m - nm) + __expf(t - nm);
          m = nm;
        }
#pragma unroll
        for (int o = 2; o; o >>= 1) {
          float mo = __shfl_xor(m, o, 64);
          float so = __shfl_xor(sum, o, 64);
          float nm = fmaxf(m, mo);
          sum = sum * __expf(m - nm) + so * __expf(mo - nm);
          m = nm;
        }
        if (lig == 0) sh[oj + i] = sc[i * SL + j] + m + __logf(sum);
      }
      __syncthreads();
    }
  }

  // ---- calibrate c = max(s at width W0)/W0 ----
  {
    int idx = tid < SL - W0 ? tid : SL - W0 - 1;
    float v = sh[rowOff(idx + W0) + idx];
#pragma unroll
    for (int o = 32; o; o >>= 1) v = fmaxf(v, __shfl_xor(v, o, 64));
    if (lane == 0) red[wave] = v;
  }
  __syncthreads();
  float cc;
  {
    float mx = red[0];
#pragma unroll
    for (int t = 1; t < 16; ++t) mx = fmaxf(mx, red[t]);
    cc = mx / (float)W0;
  }

  // ---- convert widths 1..W0 to E-space; fill Eg ----
  for (int w = 1; w <= W0; ++w) {
    for (int i = tid; i < SL - w; i += NT) {
      int j = i + w;
      int o = rowOff(j) + i;
      float E = __expf(sh[o] - cc * (float)w);
      sh[o] = E;
      Eg[i * SL + j] = E;
    }
  }
  __syncthreads();

  // ---- phase B inside: pure fma dot products ----
  insideB<4>(W0 + 1, 127, tid, sc, Eg, sh, red);
  insideB<8>(128, 191, tid, sc, Eg, sh, red);
  insideB<16>(192, 223, tid, sc, Eg, sh, red);
  insideB<32>(224, 239, tid, sc, Eg, sh, red);
  insideB<64>(240, 255, tid, sc, Eg, sh, red);

  // ---- root: g=1, H_root = exp(sc)/E ----
  if (tid == 0) {
    g[0 * SL + (SL - 1)] = 1.0f;
    float Er = sh[rowOff(SL - 1) + 0];
    float Hr = (Er > 0.f) ? __expf(sc[0 * SL + (SL - 1)]) / Er : 0.f;
    Hg[0 * SL + (SL - 1)] = Hr;
    HTg[(SL - 1) * SL + 0] = Hr;
  }
  __syncthreads();

  // ---- outside: pure fma gathers ----
  outsideB<64>(254, 240, tid, sc, g, Eg, Hg, HTg, sh);
  outsideB<32>(239, 224, tid, sc, g, Eg, Hg, HTg, sh);
  outsideB<16>(223, 192, tid, sc, g, Eg, Hg, HTg, sh);
  outsideB<8>(191, 128, tid, sc, g, Eg, Hg, HTg, sh);
  outsideB<4>(127, 1, tid, sc, g, Eg, Hg, HTg, sh);
}

// ---------------- fallback: proven global-memory kernel ----------------
__device__ __forceinline__ float grpMaxR(float v, int G) {
#pragma unroll
  for (int o = 32; o; o >>= 1)
    if (o < G) v = fmaxf(v, __shfl_xor(v, o, 64));
  return v;
}
__device__ __forceinline__ float grpSumR(float v, int G) {
#pragma unroll
  for (int o = 32; o; o >>= 1)
    if (o < G) v += __shfl_xor(v, o, 64);
  return v;
}

__global__ __launch_bounds__(NT) void cyk_io_fb(
    const float* __restrict__ scores, float* __restrict__ out,
    float* __restrict__ ws) {
  const int b = blockIdx.x;
  const int tid = threadIdx.x;
  const size_t P = (size_t)SL * SL;
  const float* sc = scores + (size_t)b * P;
  float* g = out + (size_t)b * P;
  float* s = ws + (size_t)b * P;
  float* l = ws + (size_t)(BATCH + b) * P;

  for (int i = tid; i < SL - 1; i += NT) {
    s[i * SL + i + 1] = sc[i * SL + i + 1];
    l[i * SL + i + 1] = 0.f;
  }
  __syncthreads();
  for (int w = 2; w < SL; ++w) {
    const int cells = SL - w;
    int G = NT / cells;
    G = (G >= 64) ? 64 : (1 << (31 - __clz(G)));
    const int lg = 31 - __clz(G);
    const int c = tid >> lg;
    const int lig = tid & (G - 1);
    if (c < cells) {
      const int i = c, j = i + w;
      const float* srow = s + i * SL;
      float m = -INFINITY;
      for (int k = i + 1 + lig; k < j; k += G)
        m = fmaxf(m, srow[k] + s[k * SL + j]);
      m = grpMaxR(m, G);
      float sum = 0.f;
      for (int k = i + 1 + lig; k < j; k += G)
        sum += __expf(srow[k] + s[k * SL + j] - m);
      sum = grpSumR(sum, G);
      if (lig == 0) {
        const float lse = m + __logf(sum);
        s[i * SL + j] = sc[i * SL + j] + lse;
        l[i * SL + j] = lse;
      }
    }
    __syncthreads();
  }
  if (tid == 0) g[0 * SL + (SL - 1)] = 1.0f;
  __syncthreads();
  for (int w = SL - 2; w >= 1; --w) {
    const int cells = SL - w;
    int G = NT / cells;
    G = (G >= 64) ? 64 : (1 << (31 - __clz(G)));
    const int lg = 31 - __clz(G);
    const int c = tid >> lg;
    const int lig = tid & (G - 1);
    if (c < cells) {
      const int p = c, q = p + w;
      const float spq = s[p * SL + q];
      const int TR = SL - 1 - q;
      const int T = TR + p;
      float acc = 0.f;
      for (int t = lig; t < T; t += G) {
        if (t < TR) {
          const int j = q + 1 + t;
          acc += g[p * SL + j] * __expf(spq + s[q * SL + j] - l[p * SL + j]);
        } else {
          const int i = t - TR;
          acc += g[i * SL + q] * __expf(s[i * SL + p] + spq - l[i * SL + q]);
        }
      }
      acc = grpSumR(acc, G);
      if (lig == 0) g[p * SL + q] = acc;
    }
    __syncthreads();
  }
}

extern "C" void kernel_launch(void* const* d_in, const int* in_sizes, int n_in,
                              void* d_out, int out_size, void* d_ws, size_t ws_size,
                              hipStream_t stream) {
  const float* scores = (const float*)d_in[0];
  // d_in[1] = mask: triu(k=1) broadcast -> lens == SL-1 always; unused.
  float* out = (float*)d_out;
  float* ws = (float*)d_ws;

  const size_t sq = (size_t)SL * SL * sizeof(float);       // 256 KB
  hipMemsetAsync(d_out, 0, (size_t)BATCH * sq, stream);

  int dev = 0;
  hipGetDevice(&dev);
  int maxShm = 0;
  hipDeviceGetAttribute(&maxShm, hipDeviceAttributeMaxSharedMemoryPerBlock, dev);
  (void)hipFuncSetAttribute(reinterpret_cast<const void*>(cyk_exp),
                            hipFuncAttributeMaxDynamicSharedMemorySize, LDSB);

  if (maxShm >= LDSB && ws_size >= (size_t)3 * BATCH * sq) {
    hipMemsetAsync(ws, 0, (size_t)3 * BATCH * sq, stream);  // E/H/HT guards = 0
    cyk_exp<<<BATCH, NT, LDSB, stream>>>(scores, out, ws);
  } else {
    cyk_io_fb<<<BATCH, NT, 0, stream>>>(scores, out, ws);
  }
}